// Round 16
// baseline (44.653 us; speedup 1.0000x reference)
//
#include <hip/hip_runtime.h>

#define NB  16
#define NTQ 64
#define NTV 256
#define ND  512
#define NU  512

typedef _Float16 half8_t __attribute__((ext_vector_type(8)));
typedef _Float16 half4_t __attribute__((ext_vector_type(4)));
typedef _Float16 half2_t __attribute__((ext_vector_type(2)));
typedef float floatx4 __attribute__((ext_vector_type(4)));

#if __has_builtin(__builtin_amdgcn_fdot2)
#define FDOT2(a, b, c) __builtin_amdgcn_fdot2((a), (b), (c), false)
#else
#define FDOT2(a, b, c) ((c) + (float)((a)[0]) * (float)((b)[0]) + (float)((a)[1]) * (float)((b)[1]))
#endif
#if __has_builtin(__builtin_amdgcn_rcph)
#define RCPH(x) ((_Float16)__builtin_amdgcn_rcph((_Float16)(x)))
#else
#define RCPH(x) ((_Float16)__builtin_amdgcn_rcpf((float)(x)))
#endif

__device__ __forceinline__ float wred_sum(float x) {
#pragma unroll
    for (int m = 1; m < 64; m <<= 1) x += __shfl_xor(x, m, 64);
    return x;
}
__device__ __forceinline__ float wred_max(float x) {
#pragma unroll
    for (int m = 1; m < 64; m <<= 1) x = fmaxf(x, __shfl_xor(x, m, 64));
    return x;
}

// ---------------- K1: prep = W1/W2 transpose -> f16 (blk<512) + values -> vh f16 (blk>=512)
__global__ __launch_bounds__(256) void prep_kernel(
        const float* __restrict__ W1, const float* __restrict__ W2,
        const float* __restrict__ values,
        _Float16* __restrict__ W1T, _Float16* __restrict__ W2T,
        _Float16* __restrict__ vh) {
    const int blk = blockIdx.x;
    const int t = threadIdx.x;
    __shared__ float tb[32][33];
    if (blk < 512) {
        const float* W = (blk < 256) ? W1 : W2;
        _Float16* WT = (blk < 256) ? W1T : W2T;
        const int tile = blk & 255;
        const int tr = tile >> 4, tc = tile & 15;
        const int c = t & 31, r8 = t >> 5;
#pragma unroll
        for (int i = 0; i < 4; ++i) {
            int r = r8 + 8 * i;
            tb[r][c] = W[(tr * 32 + r) * 512 + tc * 32 + c];
        }
        __syncthreads();
#pragma unroll
        for (int i = 0; i < 4; ++i) {
            int r = r8 + 8 * i;
            WT[(tc * 32 + r) * 512 + tr * 32 + c] = (_Float16)tb[c][r];
        }
    } else {
        const int base = (blk - 512) * 2048 + t * 8;
        float4 f0 = *(const float4*)(values + base);
        float4 f1 = *(const float4*)(values + base + 4);
        half8_t h;
        h[0] = (_Float16)f0.x; h[1] = (_Float16)f0.y;
        h[2] = (_Float16)f0.z; h[3] = (_Float16)f0.w;
        h[4] = (_Float16)f1.x; h[5] = (_Float16)f1.y;
        h[6] = (_Float16)f1.z; h[7] = (_Float16)f1.w;
        *(half8_t*)(vh + base) = h;
    }
}

// ---------------- K2: projections. 32x128 tiles, 640 blocks, BK=64 (8 steps),
// DISTANCE-2 prefetch: two named reg sets X/Y, loads for step k+2 issue a full
// compute phase + barrier before their vmcnt wait (~600cy slack vs dist-1 ~300).
__global__ __launch_bounds__(256, 2) void proj_gemm_kernel(
        const float* __restrict__ query, const float* __restrict__ values,
        const _Float16* __restrict__ W1T, const _Float16* __restrict__ W2T,
        const float* __restrict__ b1, const float* __restrict__ b2,
        _Float16* __restrict__ Eqh, _Float16* __restrict__ Evp) {
    __shared__ __align__(16) _Float16 As[2][32 * 72];
    __shared__ __align__(16) _Float16 Bs[2][128 * 72];
    const float KC = 2.8853900817779268f;  // 2*log2(e)
    const int bid = blockIdx.x;
    const int t = threadIdx.x;
    const int l = t & 63, w = t >> 6;

    const float* Agf; const _Float16* Bg; const float* bias; _Float16* Cg;
    int mt, nt;
    if (bid < 128) {
        mt = bid >> 2; nt = bid & 3;
        Agf = query; Bg = W1T; bias = b1; Cg = Eqh;
    } else {
        const int vb = bid - 128;
        mt = vb >> 2; nt = vb & 3;
        Agf = values; Bg = W2T; bias = b2; Cg = Evp;
    }
    const int tm = mt * 32, tn = nt * 128;

    const int arow = t >> 3, acol = (t & 7) * 8;
    const int brow = t >> 1, bcol = (t & 1) * 32;
    const float* aptr = Agf + (tm + arow) * 512 + acol;
    const _Float16* bptr = Bg + (tn + brow) * 512 + bcol;

    const int wm = (w & 1) * 16, wn = (w >> 1) * 64;
    const int lr = l & 15, lk = l >> 4;

    floatx4 acc[4] = {};
    float4 aX0, aX1; half8_t bX0, bX1, bX2, bX3;   // set X
    float4 aY0, aY1; half8_t bY0, bY1, bY2, bY3;   // set Y

#define LOAD_X(kk) do { \
        const float* ap = aptr + (kk) * 64; \
        aX0 = *(const float4*)ap; aX1 = *(const float4*)(ap + 4); \
        const _Float16* bp = bptr + (kk) * 64; \
        bX0 = *(const half8_t*)bp;        bX1 = *(const half8_t*)(bp + 8); \
        bX2 = *(const half8_t*)(bp + 16); bX3 = *(const half8_t*)(bp + 24); \
    } while (0)
#define LOAD_Y(kk) do { \
        const float* ap = aptr + (kk) * 64; \
        aY0 = *(const float4*)ap; aY1 = *(const float4*)(ap + 4); \
        const _Float16* bp = bptr + (kk) * 64; \
        bY0 = *(const half8_t*)bp;        bY1 = *(const half8_t*)(bp + 8); \
        bY2 = *(const half8_t*)(bp + 16); bY3 = *(const half8_t*)(bp + 24); \
    } while (0)
#define STORE_X(buf) do { \
        half8_t h = {(_Float16)aX0.x, (_Float16)aX0.y, (_Float16)aX0.z, (_Float16)aX0.w, \
                     (_Float16)aX1.x, (_Float16)aX1.y, (_Float16)aX1.z, (_Float16)aX1.w}; \
        *(half8_t*)(As[buf] + arow * 72 + acol) = h; \
        *(half8_t*)(Bs[buf] + brow * 72 + bcol)      = bX0; \
        *(half8_t*)(Bs[buf] + brow * 72 + bcol + 8)  = bX1; \
        *(half8_t*)(Bs[buf] + brow * 72 + bcol + 16) = bX2; \
        *(half8_t*)(Bs[buf] + brow * 72 + bcol + 24) = bX3; \
    } while (0)
#define STORE_Y(buf) do { \
        half8_t h = {(_Float16)aY0.x, (_Float16)aY0.y, (_Float16)aY0.z, (_Float16)aY0.w, \
                     (_Float16)aY1.x, (_Float16)aY1.y, (_Float16)aY1.z, (_Float16)aY1.w}; \
        *(half8_t*)(As[buf] + arow * 72 + acol) = h; \
        *(half8_t*)(Bs[buf] + brow * 72 + bcol)      = bY0; \
        *(half8_t*)(Bs[buf] + brow * 72 + bcol + 8)  = bY1; \
        *(half8_t*)(Bs[buf] + brow * 72 + bcol + 16) = bY2; \
        *(half8_t*)(Bs[buf] + brow * 72 + bcol + 24) = bY3; \
    } while (0)
#define COMPUTE(buf, koff) do { \
        half8_t af = *(const half8_t*)(As[buf] + (wm + lr) * 72 + (koff) + lk * 8); \
        half8_t bf0 = *(const half8_t*)(Bs[buf] + (wn + lr) * 72 + (koff) + lk * 8); \
        half8_t bf1 = *(const half8_t*)(Bs[buf] + (wn + 16 + lr) * 72 + (koff) + lk * 8); \
        half8_t bf2 = *(const half8_t*)(Bs[buf] + (wn + 32 + lr) * 72 + (koff) + lk * 8); \
        half8_t bf3 = *(const half8_t*)(Bs[buf] + (wn + 48 + lr) * 72 + (koff) + lk * 8); \
        acc[0] = __builtin_amdgcn_mfma_f32_16x16x32_f16(af, bf0, acc[0], 0, 0, 0); \
        acc[1] = __builtin_amdgcn_mfma_f32_16x16x32_f16(af, bf1, acc[1], 0, 0, 0); \
        acc[2] = __builtin_amdgcn_mfma_f32_16x16x32_f16(af, bf2, acc[2], 0, 0, 0); \
        acc[3] = __builtin_amdgcn_mfma_f32_16x16x32_f16(af, bf3, acc[3], 0, 0, 0); } while (0)

    LOAD_X(0);
    LOAD_Y(1);
    STORE_X(0);
    __syncthreads();

#pragma unroll 1
    for (int k2 = 0; k2 < 8; k2 += 2) {
        // even: compute buf0 (step k2); prefetch k2+2 into X; store Y (k2+1) -> buf1
        if (k2 + 2 < 8) LOAD_X(k2 + 2);
        COMPUTE(0, 0);
        COMPUTE(0, 32);
        STORE_Y(1);
        __syncthreads();
        // odd: compute buf1 (step k2+1); prefetch k2+3 into Y; store X (k2+2) -> buf0
        if (k2 + 3 < 8) LOAD_Y(k2 + 3);
        COMPUTE(1, 0);
        COMPUTE(1, 32);
        if (k2 + 2 < 8) STORE_X(0);
        __syncthreads();
    }

    // C/D layout: col = lane&15, row = (lane>>4)*4 + reg
#pragma unroll
    for (int j = 0; j < 4; ++j) {
        const int gr0 = tm + wm + lk * 4;
        const int gc = tn + wn + 16 * j + lr;
        const float bv = bias[gc];
#pragma unroll
        for (int r = 0; r < 4; ++r) {
            const float e = __builtin_amdgcn_exp2f(KC * (acc[j][r] + bv));
            Cg[(gr0 + r) * NU + gc] = (_Float16)fminf(e, 60000.f);
        }
    }
#undef LOAD_X
#undef LOAD_Y
#undef STORE_X
#undef STORE_Y
#undef COMPUTE
}

// ---------------- K3: merged score+softmax+ctx at 2q granularity.
// Phase 1 now loads Evp rows UNCONDITIONALLY 1-ahead (math stays masked): removes
// the branch-dependent load issue that exposed ~200cy L2 latency per active row.
__global__ __launch_bounds__(1024) void score_ctx_kernel(
        const _Float16* __restrict__ Eqh, const _Float16* __restrict__ Evp,
        const float* __restrict__ Vw, const int* __restrict__ enc_mask,
        const _Float16* __restrict__ vh, float* __restrict__ out) {
    const int bid = blockIdx.x;
    const int b = bid & 15, qp = bid >> 4;
    const int q0 = qp * 2;
    const int t = threadIdx.x;
    const int w = t >> 6, l = t & 63;

    __shared__ float scL8[2][256][9];    // 18 KB
    __shared__ float attL[2][256];       //  2 KB
    __shared__ float ctxp[2][8][516];    // 33 KB
    __shared__ float rs[2][4], ss[2][4];

    // ---- phase 1: score partials; wave w = v-slice (16 rows), both q per row
    {
        const half8_t eqA = *(const half8_t*)(Eqh + (b * NTQ + q0) * NU + l * 8);
        const half8_t eqB = *(const half8_t*)(Eqh + (b * NTQ + q0 + 1) * NU + l * 8);
        const float4 vwf0 = *(const float4*)(Vw + l * 8);
        const float4 vwf1 = *(const float4*)(Vw + l * 8 + 4);
        const half2_t eA0 = {eqA[0], eqA[1]}, eA1 = {eqA[2], eqA[3]},
                      eA2 = {eqA[4], eqA[5]}, eA3 = {eqA[6], eqA[7]};
        const half2_t eB0 = {eqB[0], eqB[1]}, eB1 = {eqB[2], eqB[3]},
                      eB2 = {eqB[4], eqB[5]}, eB3 = {eqB[6], eqB[7]};
        const half2_t w0 = {(_Float16)vwf0.x, (_Float16)vwf0.y},
                      w1 = {(_Float16)vwf0.z, (_Float16)vwf0.w},
                      w2 = {(_Float16)vwf1.x, (_Float16)vwf1.y},
                      w3 = {(_Float16)vwf1.z, (_Float16)vwf1.w};
        const half2_t one2 = {(_Float16)1.0f, (_Float16)1.0f};

        const int mv = (l < 16) ? enc_mask[b * NTV + w * 16 + l] : 0;
        const unsigned long long mbits = __ballot(mv != 0);

        const _Float16* evb = Evp + (b * NTV + w * 16) * NU + l * 8;
        half8_t evCur = *(const half8_t*)(evb);   // row 0, unconditional
#pragma unroll 4
        for (int r = 0; r < 16; ++r) {
            half8_t evNext = evCur;
            if (r < 15) evNext = *(const half8_t*)(evb + (r + 1) * NU);  // issue ahead
            if ((mbits >> r) & 1ull) {
                const half2_t v0 = {evCur[0], evCur[1]}, v1 = {evCur[2], evCur[3]},
                              v2 = {evCur[4], evCur[5]}, v3 = {evCur[6], evCur[7]};
                const half2_t pA0 = eA0 * v0 + one2, pA1 = eA1 * v1 + one2;
                const half2_t pA2 = eA2 * v2 + one2, pA3 = eA3 * v3 + one2;
                const half2_t pB0 = eB0 * v0 + one2, pB1 = eB1 * v1 + one2;
                const half2_t pB2 = eB2 * v2 + one2, pB3 = eB3 * v3 + one2;
                const half2_t rA0 = {RCPH(pA0[0]), RCPH(pA0[1])};
                const half2_t rB0 = {RCPH(pB0[0]), RCPH(pB0[1])};
                const half2_t rA1 = {RCPH(pA1[0]), RCPH(pA1[1])};
                const half2_t rB1 = {RCPH(pB1[0]), RCPH(pB1[1])};
                const half2_t rA2 = {RCPH(pA2[0]), RCPH(pA2[1])};
                const half2_t rB2 = {RCPH(pB2[0]), RCPH(pB2[1])};
                const half2_t rA3 = {RCPH(pA3[0]), RCPH(pA3[1])};
                const half2_t rB3 = {RCPH(pB3[0]), RCPH(pB3[1])};
                float aA = FDOT2(w0, rA0, 0.f);
                float aB = FDOT2(w0, rB0, 0.f);
                aA = FDOT2(w1, rA1, aA);
                aB = FDOT2(w1, rB1, aB);
                float cA = FDOT2(w2, rA2, 0.f);
                float cB = FDOT2(w2, rB2, 0.f);
                cA = FDOT2(w3, rA3, cA);
                cB = FDOT2(w3, rB3, cB);
                float xA = aA + cA, xB = aB + cB;
                xA += __shfl_xor(xA, 32, 64);
                xB += __shfl_xor(xB, 32, 64);
                xA += __shfl_xor(xA, 16, 64);
                xB += __shfl_xor(xB, 16, 64);
                xA += __shfl_xor(xA, 8, 64);
                xB += __shfl_xor(xB, 8, 64);
                if (l < 8) {
                    scL8[0][w * 16 + r][l] = xA;
                    scL8[1][w * 16 + r][l] = xB;
                }
            } else if (l < 8) {
                scL8[0][w * 16 + r][l] = 0.f;
                scL8[1][w * 16 + r][l] = 0.f;
            }
            evCur = evNext;
        }
    }
    __syncthreads();

    // ---- phase 2: softmax (threads 0..511: q = t>>8, v = t&255)
    if (t < 512) {
        const int q = t >> 8, v = t & 255;
        const int w4 = (t >> 6) & 3;
        float s = 0.f;
#pragma unroll
        for (int i = 0; i < 8; ++i) s += scL8[q][v][i];
        float sc = -2.f * s;                          // CVb dropped: shift-invariant
        sc -= enc_mask[b * NTV + v] ? 0.f : 1e9f;
        float m = wred_max(sc);
        if (l == 0) rs[q][w4] = m;
        __syncthreads();
        m = fmaxf(fmaxf(rs[q][0], rs[q][1]), fmaxf(rs[q][2], rs[q][3]));
        const float LOG2E = 1.4426950408889634f;
        const float ee = __builtin_amdgcn_exp2f((sc - m) * LOG2E);
        float t0 = wred_sum(ee);
        if (l == 0) ss[q][w4] = t0;
        __syncthreads();
        const float S = (ss[q][0] + ss[q][1]) + (ss[q][2] + ss[q][3]);
        const float a = ee * __builtin_amdgcn_rcpf(S);
        attL[q][v] = a;
        float* out_attn = out + NB * NTQ * ND;
        out_attn[(b * NTQ + q0 + q) * NTV + v] = a;
    } else {
        __syncthreads();
        __syncthreads();
    }
    __syncthreads();

    // ---- phase 3: context; mask-skip vi, f16 vh half4 loads
    {
        const int vg = t >> 7;
        const int dq = t & 127;
        const unsigned long long mb2 = __ballot(enc_mask[b * NTV + vg * 32 + l] != 0);
        const _Float16* vsrc = vh + (b * NTV + vg * 32) * ND + dq * 4;
        floatx4 c0 = {0.f, 0.f, 0.f, 0.f}, c1 = {0.f, 0.f, 0.f, 0.f};
#pragma unroll 4
        for (int vi = 0; vi < 32; ++vi) {
            if ((mb2 >> vi) & 1ull) {
                const half4_t vvh = *(const half4_t*)(vsrc + vi * ND);
                const floatx4 vv = {(float)vvh[0], (float)vvh[1], (float)vvh[2], (float)vvh[3]};
                const int v = vg * 32 + vi;
                const float aw0 = attL[0][v], aw1 = attL[1][v];
#pragma unroll
                for (int j = 0; j < 4; ++j) {
                    c0[j] = fmaf(aw0, vv[j], c0[j]);
                    c1[j] = fmaf(aw1, vv[j], c1[j]);
                }
            }
        }
        *(floatx4*)&ctxp[0][vg][dq * 4] = c0;
        *(floatx4*)&ctxp[1][vg][dq * 4] = c1;
    }
    __syncthreads();
    {
        const int cq = t >> 9, d = t & 511;
        float s = ((ctxp[cq][0][d] + ctxp[cq][1][d]) + (ctxp[cq][2][d] + ctxp[cq][3][d]))
                + ((ctxp[cq][4][d] + ctxp[cq][5][d]) + (ctxp[cq][6][d] + ctxp[cq][7][d]));
        out[(b * NTQ + q0 + cq) * ND + d] = s;
    }
}

extern "C" void kernel_launch(void* const* d_in, const int* in_sizes, int n_in,
                              void* d_out, int out_size, void* d_ws, size_t ws_size,
                              hipStream_t stream) {
    const float* query  = (const float*)d_in[0];
    const float* values = (const float*)d_in[1];
    const int*   emask  = (const int*)d_in[2];
    const float* W1     = (const float*)d_in[3];
    const float* b1     = (const float*)d_in[4];
    const float* W2     = (const float*)d_in[5];
    const float* b2     = (const float*)d_in[6];
    const float* Vw     = (const float*)d_in[7];
    float* out = (float*)d_out;

    char* ws = (char*)d_ws;
    _Float16* W1T = (_Float16*)(ws + 0);          //  512 KB [U][D] f16
    _Float16* W2T = (_Float16*)(ws + 524288);     //  512 KB [U][D] f16
    _Float16* vh  = (_Float16*)(ws + 2097152);    //    4 MB [B*TV][D] f16
    _Float16* Eqh = (_Float16*)(ws + 6291456);    //    1 MB [B*TQ][U] f16 exp2
    _Float16* Evp = (_Float16*)(ws + 7340032);    //    4 MB [B][TV][U] f16 exp2 (v-major)

    prep_kernel<<<dim3(1536), dim3(256), 0, stream>>>(W1, W2, values, W1T, W2T, vh);
    proj_gemm_kernel<<<dim3(640), dim3(256), 0, stream>>>(query, values, W1T, W2T,
                                                          b1, b2, Eqh, Evp);
    score_ctx_kernel<<<dim3(512), dim3(1024), 0, stream>>>(Eqh, Evp, Vw, emask, vh, out);
}

// Round 17
// 43.164 us; speedup vs baseline: 1.0345x; 1.0345x over previous
//
#include <hip/hip_runtime.h>

#define NB  16
#define NTQ 64
#define NTV 256
#define ND  512
#define NU  512

typedef _Float16 half8_t __attribute__((ext_vector_type(8)));
typedef _Float16 half4_t __attribute__((ext_vector_type(4)));
typedef _Float16 half2_t __attribute__((ext_vector_type(2)));
typedef float floatx4 __attribute__((ext_vector_type(4)));

#if __has_builtin(__builtin_amdgcn_fdot2)
#define FDOT2(a, b, c) __builtin_amdgcn_fdot2((a), (b), (c), false)
#else
#define FDOT2(a, b, c) ((c) + (float)((a)[0]) * (float)((b)[0]) + (float)((a)[1]) * (float)((b)[1]))
#endif
#if __has_builtin(__builtin_amdgcn_rcph)
#define RCPH(x) ((_Float16)__builtin_amdgcn_rcph((_Float16)(x)))
#else
#define RCPH(x) ((_Float16)__builtin_amdgcn_rcpf((float)(x)))
#endif

__device__ __forceinline__ float wred_sum(float x) {
#pragma unroll
    for (int m = 1; m < 64; m <<= 1) x += __shfl_xor(x, m, 64);
    return x;
}
__device__ __forceinline__ float wred_max(float x) {
#pragma unroll
    for (int m = 1; m < 64; m <<= 1) x = fmaxf(x, __shfl_xor(x, m, 64));
    return x;
}

// ---------------- K1: prep = W1/W2 transpose -> f16 (blk<512) + values -> vh f16 (blk>=512)
__global__ __launch_bounds__(256) void prep_kernel(
        const float* __restrict__ W1, const float* __restrict__ W2,
        const float* __restrict__ values,
        _Float16* __restrict__ W1T, _Float16* __restrict__ W2T,
        _Float16* __restrict__ vh) {
    const int blk = blockIdx.x;
    const int t = threadIdx.x;
    __shared__ float tb[32][33];
    if (blk < 512) {
        const float* W = (blk < 256) ? W1 : W2;
        _Float16* WT = (blk < 256) ? W1T : W2T;
        const int tile = blk & 255;
        const int tr = tile >> 4, tc = tile & 15;
        const int c = t & 31, r8 = t >> 5;
#pragma unroll
        for (int i = 0; i < 4; ++i) {
            int r = r8 + 8 * i;
            tb[r][c] = W[(tr * 32 + r) * 512 + tc * 32 + c];
        }
        __syncthreads();
#pragma unroll
        for (int i = 0; i < 4; ++i) {
            int r = r8 + 8 * i;
            WT[(tc * 32 + r) * 512 + tr * 32 + c] = (_Float16)tb[c][r];
        }
    } else {
        const int base = (blk - 512) * 2048 + t * 8;
        float4 f0 = *(const float4*)(values + base);
        float4 f1 = *(const float4*)(values + base + 4);
        half8_t h;
        h[0] = (_Float16)f0.x; h[1] = (_Float16)f0.y;
        h[2] = (_Float16)f0.z; h[3] = (_Float16)f0.w;
        h[4] = (_Float16)f1.x; h[5] = (_Float16)f1.y;
        h[6] = (_Float16)f1.z; h[7] = (_Float16)f1.w;
        *(half8_t*)(vh + base) = h;
    }
}

// ---------------- K2: projections. 32x128 tiles, 640 blocks, BK=64 (8 steps, 8 barriers,
// 8 MFMA/barrier), dist-1 reg prefetch, dbuf LDS.
__global__ __launch_bounds__(256, 2) void proj_gemm_kernel(
        const float* __restrict__ query, const float* __restrict__ values,
        const _Float16* __restrict__ W1T, const _Float16* __restrict__ W2T,
        const float* __restrict__ b1, const float* __restrict__ b2,
        _Float16* __restrict__ Eqh, _Float16* __restrict__ Evp) {
    __shared__ __align__(16) _Float16 As[2][32 * 72];
    __shared__ __align__(16) _Float16 Bs[2][128 * 72];
    const float KC = 2.8853900817779268f;  // 2*log2(e)
    const int bid = blockIdx.x;
    const int t = threadIdx.x;
    const int l = t & 63, w = t >> 6;

    const float* Agf; const _Float16* Bg; const float* bias; _Float16* Cg;
    int mt, nt;
    if (bid < 128) {
        mt = bid >> 2; nt = bid & 3;
        Agf = query; Bg = W1T; bias = b1; Cg = Eqh;
    } else {
        const int vb = bid - 128;
        mt = vb >> 2; nt = vb & 3;
        Agf = values; Bg = W2T; bias = b2; Cg = Evp;
    }
    const int tm = mt * 32, tn = nt * 128;

    // staging: A 32 rows x 64 k f32 (8 f32/thread); B 128 rows x 64 k f16 (32 f16/thread)
    const int arow = t >> 3, acol = (t & 7) * 8;
    const int brow = t >> 1, bcol = (t & 1) * 32;
    const float* aptr = Agf + (tm + arow) * 512 + acol;
    const _Float16* bptr = Bg + (tn + brow) * 512 + bcol;

    const int wm = (w & 1) * 16, wn = (w >> 1) * 64;
    const int lr = l & 15, lk = l >> 4;

    floatx4 acc[4] = {};
    float4 aX0, aX1; half8_t bX0, bX1, bX2, bX3;

#define LOADK(kk) do { \
        const float* ap = aptr + (kk) * 64; \
        aX0 = *(const float4*)ap; aX1 = *(const float4*)(ap + 4); \
        const _Float16* bp = bptr + (kk) * 64; \
        bX0 = *(const half8_t*)bp;        bX1 = *(const half8_t*)(bp + 8); \
        bX2 = *(const half8_t*)(bp + 16); bX3 = *(const half8_t*)(bp + 24); \
    } while (0)
#define STOREK(buf) do { \
        half8_t h = {(_Float16)aX0.x, (_Float16)aX0.y, (_Float16)aX0.z, (_Float16)aX0.w, \
                     (_Float16)aX1.x, (_Float16)aX1.y, (_Float16)aX1.z, (_Float16)aX1.w}; \
        *(half8_t*)(As[buf] + arow * 72 + acol) = h; \
        *(half8_t*)(Bs[buf] + brow * 72 + bcol)      = bX0; \
        *(half8_t*)(Bs[buf] + brow * 72 + bcol + 8)  = bX1; \
        *(half8_t*)(Bs[buf] + brow * 72 + bcol + 16) = bX2; \
        *(half8_t*)(Bs[buf] + brow * 72 + bcol + 24) = bX3; \
    } while (0)
#define COMPUTE(buf, koff) do { \
        half8_t af = *(const half8_t*)(As[buf] + (wm + lr) * 72 + (koff) + lk * 8); \
        half8_t bf0 = *(const half8_t*)(Bs[buf] + (wn + lr) * 72 + (koff) + lk * 8); \
        half8_t bf1 = *(const half8_t*)(Bs[buf] + (wn + 16 + lr) * 72 + (koff) + lk * 8); \
        half8_t bf2 = *(const half8_t*)(Bs[buf] + (wn + 32 + lr) * 72 + (koff) + lk * 8); \
        half8_t bf3 = *(const half8_t*)(Bs[buf] + (wn + 48 + lr) * 72 + (koff) + lk * 8); \
        acc[0] = __builtin_amdgcn_mfma_f32_16x16x32_f16(af, bf0, acc[0], 0, 0, 0); \
        acc[1] = __builtin_amdgcn_mfma_f32_16x16x32_f16(af, bf1, acc[1], 0, 0, 0); \
        acc[2] = __builtin_amdgcn_mfma_f32_16x16x32_f16(af, bf2, acc[2], 0, 0, 0); \
        acc[3] = __builtin_amdgcn_mfma_f32_16x16x32_f16(af, bf3, acc[3], 0, 0, 0); } while (0)

    LOADK(0);
    STOREK(0);
    __syncthreads();

#pragma unroll 1
    for (int kk = 0; kk < 8; ++kk) {
        const int cur = kk & 1;
        if (kk < 7) LOADK(kk + 1);       // issue early: hides under 8 MFMAs + ds_reads
        COMPUTE(cur, 0);
        COMPUTE(cur, 32);
        if (kk < 7) STOREK(cur ^ 1);     // write late into other buffer
        __syncthreads();                 // one barrier per 64-K step
    }

    // C/D layout: col = lane&15, row = (lane>>4)*4 + reg
#pragma unroll
    for (int j = 0; j < 4; ++j) {
        const int gr0 = tm + wm + lk * 4;
        const int gc = tn + wn + 16 * j + lr;
        const float bv = bias[gc];
#pragma unroll
        for (int r = 0; r < 4; ++r) {
            const float e = __builtin_amdgcn_exp2f(KC * (acc[j][r] + bv));
            Cg[(gr0 + r) * NU + gc] = (_Float16)fminf(e, 60000.f);
        }
    }
#undef LOADK
#undef STOREK
#undef COMPUTE
}

// ---------------- K3: merged score+softmax+ctx at 2q granularity (R13 structure;
// phase 3 reads f16 vh -> halved L2 stream)
__global__ __launch_bounds__(1024) void score_ctx_kernel(
        const _Float16* __restrict__ Eqh, const _Float16* __restrict__ Evp,
        const float* __restrict__ Vw, const int* __restrict__ enc_mask,
        const _Float16* __restrict__ vh, float* __restrict__ out) {
    const int bid = blockIdx.x;
    const int b = bid & 15, qp = bid >> 4;
    const int q0 = qp * 2;
    const int t = threadIdx.x;
    const int w = t >> 6, l = t & 63;

    __shared__ float scL8[2][256][9];    // 18 KB
    __shared__ float attL[2][256];       //  2 KB
    __shared__ float ctxp[2][8][516];    // 33 KB
    __shared__ float rs[2][4], ss[2][4];

    // ---- phase 1: score partials; wave w = v-slice (16 rows), both q per row
    {
        const half8_t eqA = *(const half8_t*)(Eqh + (b * NTQ + q0) * NU + l * 8);
        const half8_t eqB = *(const half8_t*)(Eqh + (b * NTQ + q0 + 1) * NU + l * 8);
        const float4 vwf0 = *(const float4*)(Vw + l * 8);
        const float4 vwf1 = *(const float4*)(Vw + l * 8 + 4);
        const half2_t eA0 = {eqA[0], eqA[1]}, eA1 = {eqA[2], eqA[3]},
                      eA2 = {eqA[4], eqA[5]}, eA3 = {eqA[6], eqA[7]};
        const half2_t eB0 = {eqB[0], eqB[1]}, eB1 = {eqB[2], eqB[3]},
                      eB2 = {eqB[4], eqB[5]}, eB3 = {eqB[6], eqB[7]};
        const half2_t w0 = {(_Float16)vwf0.x, (_Float16)vwf0.y},
                      w1 = {(_Float16)vwf0.z, (_Float16)vwf0.w},
                      w2 = {(_Float16)vwf1.x, (_Float16)vwf1.y},
                      w3 = {(_Float16)vwf1.z, (_Float16)vwf1.w};
        const half2_t one2 = {(_Float16)1.0f, (_Float16)1.0f};

        const int mv = (l < 16) ? enc_mask[b * NTV + w * 16 + l] : 0;
        const unsigned long long mbits = __ballot(mv != 0);

        const _Float16* evb = Evp + (b * NTV + w * 16) * NU + l * 8;
#pragma unroll 4
        for (int r = 0; r < 16; ++r) {
            if ((mbits >> r) & 1ull) {
                const half8_t ev8 = *(const half8_t*)(evb + r * NU);
                const half2_t v0 = {ev8[0], ev8[1]}, v1 = {ev8[2], ev8[3]},
                              v2 = {ev8[4], ev8[5]}, v3 = {ev8[6], ev8[7]};
                const half2_t pA0 = eA0 * v0 + one2, pA1 = eA1 * v1 + one2;
                const half2_t pA2 = eA2 * v2 + one2, pA3 = eA3 * v3 + one2;
                const half2_t pB0 = eB0 * v0 + one2, pB1 = eB1 * v1 + one2;
                const half2_t pB2 = eB2 * v2 + one2, pB3 = eB3 * v3 + one2;
                const half2_t rA0 = {RCPH(pA0[0]), RCPH(pA0[1])};
                const half2_t rB0 = {RCPH(pB0[0]), RCPH(pB0[1])};
                const half2_t rA1 = {RCPH(pA1[0]), RCPH(pA1[1])};
                const half2_t rB1 = {RCPH(pB1[0]), RCPH(pB1[1])};
                const half2_t rA2 = {RCPH(pA2[0]), RCPH(pA2[1])};
                const half2_t rB2 = {RCPH(pB2[0]), RCPH(pB2[1])};
                const half2_t rA3 = {RCPH(pA3[0]), RCPH(pA3[1])};
                const half2_t rB3 = {RCPH(pB3[0]), RCPH(pB3[1])};
                float aA = FDOT2(w0, rA0, 0.f);
                float aB = FDOT2(w0, rB0, 0.f);
                aA = FDOT2(w1, rA1, aA);
                aB = FDOT2(w1, rB1, aB);
                float cA = FDOT2(w2, rA2, 0.f);
                float cB = FDOT2(w2, rB2, 0.f);
                cA = FDOT2(w3, rA3, cA);
                cB = FDOT2(w3, rB3, cB);
                float xA = aA + cA, xB = aB + cB;
                xA += __shfl_xor(xA, 32, 64);
                xB += __shfl_xor(xB, 32, 64);
                xA += __shfl_xor(xA, 16, 64);
                xB += __shfl_xor(xB, 16, 64);
                xA += __shfl_xor(xA, 8, 64);
                xB += __shfl_xor(xB, 8, 64);
                if (l < 8) {
                    scL8[0][w * 16 + r][l] = xA;
                    scL8[1][w * 16 + r][l] = xB;
                }
            } else if (l < 8) {
                scL8[0][w * 16 + r][l] = 0.f;
                scL8[1][w * 16 + r][l] = 0.f;
            }
        }
    }
    __syncthreads();

    // ---- phase 2: softmax (threads 0..511: q = t>>8, v = t&255)
    if (t < 512) {
        const int q = t >> 8, v = t & 255;
        const int w4 = (t >> 6) & 3;
        float s = 0.f;
#pragma unroll
        for (int i = 0; i < 8; ++i) s += scL8[q][v][i];
        float sc = -2.f * s;                          // CVb dropped: shift-invariant
        sc -= enc_mask[b * NTV + v] ? 0.f : 1e9f;
        float m = wred_max(sc);
        if (l == 0) rs[q][w4] = m;
        __syncthreads();
        m = fmaxf(fmaxf(rs[q][0], rs[q][1]), fmaxf(rs[q][2], rs[q][3]));
        const float LOG2E = 1.4426950408889634f;
        const float ee = __builtin_amdgcn_exp2f((sc - m) * LOG2E);
        float t0 = wred_sum(ee);
        if (l == 0) ss[q][w4] = t0;
        __syncthreads();
        const float S = (ss[q][0] + ss[q][1]) + (ss[q][2] + ss[q][3]);
        const float a = ee * __builtin_amdgcn_rcpf(S);
        attL[q][v] = a;
        float* out_attn = out + NB * NTQ * ND;
        out_attn[(b * NTQ + q0 + q) * NTV + v] = a;
    } else {
        __syncthreads();
        __syncthreads();
    }
    __syncthreads();

    // ---- phase 3: context; mask-skip vi, f16 vh half4 loads (halved L2 stream)
    {
        const int vg = t >> 7;
        const int dq = t & 127;
        const unsigned long long mb2 = __ballot(enc_mask[b * NTV + vg * 32 + l] != 0);
        const _Float16* vsrc = vh + (b * NTV + vg * 32) * ND + dq * 4;
        floatx4 c0 = {0.f, 0.f, 0.f, 0.f}, c1 = {0.f, 0.f, 0.f, 0.f};
#pragma unroll 4
        for (int vi = 0; vi < 32; ++vi) {
            if ((mb2 >> vi) & 1ull) {
                const half4_t vvh = *(const half4_t*)(vsrc + vi * ND);
                const floatx4 vv = {(float)vvh[0], (float)vvh[1], (float)vvh[2], (float)vvh[3]};
                const int v = vg * 32 + vi;
                const float aw0 = attL[0][v], aw1 = attL[1][v];
#pragma unroll
                for (int j = 0; j < 4; ++j) {
                    c0[j] = fmaf(aw0, vv[j], c0[j]);
                    c1[j] = fmaf(aw1, vv[j], c1[j]);
                }
            }
        }
        *(floatx4*)&ctxp[0][vg][dq * 4] = c0;
        *(floatx4*)&ctxp[1][vg][dq * 4] = c1;
    }
    __syncthreads();
    {
        const int cq = t >> 9, d = t & 511;
        float s = ((ctxp[cq][0][d] + ctxp[cq][1][d]) + (ctxp[cq][2][d] + ctxp[cq][3][d]))
                + ((ctxp[cq][4][d] + ctxp[cq][5][d]) + (ctxp[cq][6][d] + ctxp[cq][7][d]));
        out[(b * NTQ + q0 + cq) * ND + d] = s;
    }
}

extern "C" void kernel_launch(void* const* d_in, const int* in_sizes, int n_in,
                              void* d_out, int out_size, void* d_ws, size_t ws_size,
                              hipStream_t stream) {
    const float* query  = (const float*)d_in[0];
    const float* values = (const float*)d_in[1];
    const int*   emask  = (const int*)d_in[2];
    const float* W1     = (const float*)d_in[3];
    const float* b1     = (const float*)d_in[4];
    const float* W2     = (const float*)d_in[5];
    const float* b2     = (const float*)d_in[6];
    const float* Vw     = (const float*)d_in[7];
    float* out = (float*)d_out;

    char* ws = (char*)d_ws;
    _Float16* W1T = (_Float16*)(ws + 0);          //  512 KB [U][D] f16
    _Float16* W2T = (_Float16*)(ws + 524288);     //  512 KB [U][D] f16
    _Float16* vh  = (_Float16*)(ws + 2097152);    //    4 MB [B*TV][D] f16
    _Float16* Eqh = (_Float16*)(ws + 6291456);    //    1 MB [B*TQ][U] f16 exp2
    _Float16* Evp = (_Float16*)(ws + 7340032);    //    4 MB [B][TV][U] f16 exp2 (v-major)

    prep_kernel<<<dim3(1536), dim3(256), 0, stream>>>(W1, W2, values, W1T, W2T, vh);
    proj_gemm_kernel<<<dim3(640), dim3(256), 0, stream>>>(query, values, W1T, W2T,
                                                          b1, b2, Eqh, Evp);
    score_ctx_kernel<<<dim3(512), dim3(1024), 0, stream>>>(Eqh, Evp, Vw, emask, vh, out);
}